// Round 4
// baseline (407.232 us; speedup 1.0000x reference)
//
#include <hip/hip_runtime.h>
#include <math.h>

// DiffKS round 4: single-kernel producer/consumer pipeline (1 block, 4 waves).
//   Wave 0  = consumer: serial KS recursion, chunk KC=49 (2*49=98 < 101 min
//             dependency distance => 2-ahead LDS pipelining). Hot loop has NO
//             vmem loads: taps come from an LDS ring filled by producers.
//   Waves 1-3 = producers: per-sample taps v[0..6] + hist byte-offset q,
//             computed from LDS-staged frame tables, written to a 16-body
//             (32 KB) LDS ring in 8-body blocks, round-robin.
//   Sync: volatile LDS counters + __threadfence_block(). Producers need
//   cons >= B*8-8 (16-slot ring safety); consumer needs producers >= G+12.
//   Traced: no deadlock, producers self-sustain 1-2 blocks ahead.

#define T_SAMPLES 44100
#define NFRAMES   100
#define BURST     2048
#define KC        49
#define NB        900            // 900*49 = 44100
#define HISTSZ    1032           // 1024 ring + 7 mirror + pad
#define RB        16             // ring bodies (power of 2)
#define NPROD     3

__global__ __launch_bounds__(256, 1) void diffks_fused(
    const float* __restrict__ delay_frames,   // (100,)
    const float* __restrict__ excitation,     // (2048,)
    const float* __restrict__ raw_coeff,      // (100,6)
    const float* __restrict__ raw_gain,       // (1,)
    const float* __restrict__ exc_coeff,      // (100,5)
    float* __restrict__ out)                  // (44100,) f32
{
    // pool: phase 0/1 scratch (s_tail, s_nb) aliased with phase-2 tap ring
    __shared__ __align__(16) float s_pool[RB * 512];   // 32 KB
    __shared__ float s_x[64][33];                      // burst, padded rows
    __shared__ float s_hist[HISTSZ];
    __shared__ __align__(16) float s_cf[NFRAMES][12];  // c0..c5, d0..d5
    __shared__ float2 s_dd[NFRAMES];                   // delay, ddelta
    __shared__ float s_ec[NFRAMES][10];                // exc e0..e4, de0..de4
    __shared__ float s_bound[64][6];
    __shared__ int   s_sync[8];                        // 0..2 prod, 3 cons

    float (*s_tail)[32] = (float(*)[32])s_pool;        // 64x32 (phase 1)
    float (*s_nb)[8]    = (float(*)[8])(s_pool + 2048);// 100x8  (phase 0)
    float* s_ring = s_pool;                            // phase 2

    const int tid  = threadIdx.x;
    const int wid  = tid >> 6;
    const int lane = tid & 63;
    const float gain  = 0.1f / (1.0f + expf(-raw_gain[0])) + 0.9f;
    const float stepT = 99.0f / (float)(T_SAMPLES - 1);
    const float stepE = 99.0f / (float)(BURST - 1);

    // ---------------- phase 0: stage everything ----------------
    for (int t = tid; t < BURST; t += 256)
        s_x[t >> 5][t & 31] = excitation[t];
    if (tid < NFRAMES) {                       // sigmoid-normalized loop coefs
        float sb[6]; float s = 0.f;
        #pragma unroll
        for (int j = 0; j < 6; ++j) {
            sb[j] = 1.0f / (1.0f + expf(-raw_coeff[tid * 6 + j]));
            s += sb[j];
        }
        float inv = gain / s;
        #pragma unroll
        for (int j = 0; j < 6; ++j) s_nb[tid][j] = sb[j] * inv;
    }
    if (tid < NFRAMES - 1) {                   // delay + delta
        float d0 = delay_frames[tid], d1 = delay_frames[tid + 1];
        s_dd[tid] = make_float2(d0, d1 - d0);
        #pragma unroll
        for (int k = 0; k < 5; ++k) {          // exc coefs + deltas
            float a0 = exc_coeff[tid * 5 + k];
            float a1 = exc_coeff[(tid + 1) * 5 + k];
            s_ec[tid][k] = a0;
            s_ec[tid][5 + k] = a1 - a0;
        }
    }
    for (int i = tid; i < HISTSZ; i += 256) s_hist[i] = 0.0f;
    if (tid < 8) s_sync[tid] = (tid < NPROD) ? (8 * tid - 16) : 0;
    __syncthreads();
    if (tid < NFRAMES - 1) {                   // cf rows: coef + delta
        #pragma unroll
        for (int j = 0; j < 6; ++j) {
            s_cf[tid][j]     = s_nb[tid][j];
            s_cf[tid][6 + j] = s_nb[tid + 1][j] - s_nb[tid][j];
        }
    }
    __syncthreads();

    // ---------------- phase 1: excitation LPC (64-segment scan) ----------------
    if (tid < 64) {                            // pass 1: particular + 5 homog
        float st[6][5];
        #pragma unroll
        for (int r = 0; r < 6; ++r)
            #pragma unroll
            for (int k = 0; k < 5; ++k) st[r][k] = 0.0f;
        #pragma unroll
        for (int r = 1; r <= 5; ++r) st[r][r - 1] = 1.0f;
        for (int i = 0; i < 32; ++i) {
            int te = lane * 32 + i;
            float pos = (float)te * stepE;
            int i0 = (int)pos; i0 = min(i0, NFRAMES - 2);
            float w = pos - (float)i0;
            const float* e = s_ec[i0];
            float a0 = fmaf(w, e[5], e[0]);
            float a1 = fmaf(w, e[6], e[1]);
            float a2 = fmaf(w, e[7], e[2]);
            float a3 = fmaf(w, e[8], e[3]);
            float a4 = fmaf(w, e[9], e[4]);
            float xv = s_x[lane][i];
            #pragma unroll
            for (int r = 0; r < 6; ++r) {
                float acc = (r == 0) ? xv : 0.0f;
                acc = fmaf(-a0, st[r][0], acc);
                acc = fmaf(-a1, st[r][1], acc);
                acc = fmaf(-a2, st[r][2], acc);
                acc = fmaf(-a3, st[r][3], acc);
                acc = fmaf(-a4, st[r][4], acc);
                st[r][4] = st[r][3]; st[r][3] = st[r][2];
                st[r][2] = st[r][1]; st[r][1] = st[r][0];
                st[r][0] = acc;
            }
        }
        #pragma unroll
        for (int r = 0; r < 6; ++r)
            #pragma unroll
            for (int k = 0; k < 5; ++k) s_tail[lane][r * 5 + k] = st[r][k];
    }
    __syncthreads();
    if (tid == 0) {                            // pass 2: chain boundary states
        float Y[5] = {0.f, 0.f, 0.f, 0.f, 0.f};
        for (int l = 0; l < 64; ++l) {
            #pragma unroll
            for (int c = 0; c < 5; ++c) s_bound[l][c] = Y[c];
            float tl[30];
            #pragma unroll
            for (int j = 0; j < 30; ++j) tl[j] = s_tail[l][j];
            float ny[5];
            #pragma unroll
            for (int k = 0; k < 5; ++k) {
                float acc = tl[k];
                #pragma unroll
                for (int c = 1; c <= 5; ++c)
                    acc = fmaf(tl[c * 5 + k], Y[c - 1], acc);
                ny[k] = acc;
            }
            #pragma unroll
            for (int k = 0; k < 5; ++k) Y[k] = ny[k];
        }
    }
    __syncthreads();
    if (tid < 64) {                            // pass 3: re-run w/ boundaries
        float b0 = s_bound[lane][0], b1 = s_bound[lane][1], b2 = s_bound[lane][2];
        float b3 = s_bound[lane][3], b4 = s_bound[lane][4];
        for (int i = 0; i < 32; ++i) {
            int te = lane * 32 + i;
            float pos = (float)te * stepE;
            int i0 = (int)pos; i0 = min(i0, NFRAMES - 2);
            float w = pos - (float)i0;
            const float* e = s_ec[i0];
            float a0 = fmaf(w, e[5], e[0]);
            float a1 = fmaf(w, e[6], e[1]);
            float a2 = fmaf(w, e[7], e[2]);
            float a3 = fmaf(w, e[8], e[3]);
            float a4 = fmaf(w, e[9], e[4]);
            float acc = s_x[lane][i];
            acc = fmaf(-a0, b0, acc);
            acc = fmaf(-a1, b1, acc);
            acc = fmaf(-a2, b2, acc);
            acc = fmaf(-a3, b3, acc);
            acc = fmaf(-a4, b4, acc);
            b4 = b3; b3 = b2; b2 = b1; b1 = b0; b0 = acc;
            s_x[lane][i] = acc;
        }
    }
    __syncthreads();
    // zero the tap ring (aliases phase-1 scratch; also covers lanes 49-63)
    for (int i = tid; i < RB * 512; i += 256) s_ring[i] = 0.0f;
    __syncthreads();

    // ---------------- phase 2: decoupled pipeline ----------------
    if (wid == 0) {
        // ===== consumer =====
        const bool act = lane < KC;
        volatile int* vs = s_sync;
        auto poll_ready = [&](int target) {
            for (;;) {
                int m = min(min(vs[0], vs[1]), vs[2]) + 16;
                if (m >= target) break;
                __builtin_amdgcn_s_sleep(1);
            }
            __threadfence_block();
        };

        poll_ready(12);
        float4 rA[4], rB[4];
        #pragma unroll
        for (int s = 0; s < 4; ++s) {
            const float4* rp = (const float4*)&s_ring[(s & (RB - 1)) * 512 + lane * 8];
            rA[s] = rp[0]; rB[s] = rp[1];
        }
        float hu0[7], hu1[7];
        #pragma unroll
        for (int k = 0; k < 7; ++k) { hu0[k] = 0.f; hu1[k] = 0.f; }
        int t = lane;

        // body macro: c = G+J; reg slot J&3; hist buf by parity (G%8==0)
        #define CBODY(J, HU)                                                   \
        {                                                                      \
            const float4 a = rA[(J) & 3];                                      \
            const float4 b = rB[(J) & 3];                                      \
            float acc = 0.0f;                                                  \
            if (G + (J) <= 41) {                                               \
                if (act && t < BURST) acc = s_x[t >> 5][t & 31];               \
            }                                                                  \
            acc = fmaf(-a.x, HU[6], acc);                                      \
            acc = fmaf(-a.y, HU[5], acc);                                      \
            acc = fmaf(-a.z, HU[4], acc);                                      \
            acc = fmaf(-a.w, HU[3], acc);                                      \
            acc = fmaf(-b.x, HU[2], acc);                                      \
            acc = fmaf(-b.y, HU[1], acc);                                      \
            acc = fmaf(-b.z, HU[0], acc);                                      \
            int p = t & 1023;                                                  \
            if (act) s_hist[p] = acc;                                          \
            {   int pm = ((G + (J)) * KC) & 1023;                              \
                if (pm >= 976 || pm < 7) {                                     \
                    if (act && p < 7) s_hist[p + 1024] = acc;                  \
                } }                                                            \
            if (act) out[t] = acc;                                            \
            {   int qb = __float_as_int(rB[((J) + 2) & 3].w);                  \
                qb = min(qb, 4092);                                            \
                const float* hp = (const float*)((const char*)s_hist + qb);    \
                HU[0] = hp[0]; HU[1] = hp[1]; HU[2] = hp[2]; HU[3] = hp[3];    \
                HU[4] = hp[4]; HU[5] = hp[5]; HU[6] = hp[6]; }                 \
            {   int nb_ = G + (J) + 4; if (nb_ > NB - 1) nb_ = NB - 1;         \
                const float4* rp =                                             \
                    (const float4*)&s_ring[(nb_ & (RB - 1)) * 512 + lane * 8]; \
                rA[(J) & 3] = rp[0]; rB[(J) & 3] = rp[1]; }                    \
            t += KC;                                                           \
        }

        int G = 0;
        for (; G < 896; G += 8) {
            if (G) poll_ready(min(G + 12, NB));
            CBODY(0, hu0) CBODY(1, hu1) CBODY(2, hu0) CBODY(3, hu1)
            CBODY(4, hu0) CBODY(5, hu1) CBODY(6, hu0) CBODY(7, hu1)
            __threadfence_block();
            if (lane == 0) vs[3] = G + 8;
        }
        // tail: bodies 896..899 (G == 896 here)
        poll_ready(NB);
        CBODY(0, hu0) CBODY(1, hu1) CBODY(2, hu0) CBODY(3, hu1)
        #undef CBODY
    } else {
        // ===== producers =====
        const int pidx = wid - 1;              // 0..2
        const bool act = lane < KC;
        volatile int* vs = s_sync;
        for (int B = pidx; B * 8 < NB; B += NPROD) {
            const int b0 = B * 8;
            const int limit = b0 - 8;          // 16-slot ring safety
            while (vs[3] < limit) __builtin_amdgcn_s_sleep(4);
            __threadfence_block();
            const int bend = min(b0 + 8, NB);
            for (int b = b0; b < bend; ++b) {
                int tt = b * KC + lane;
                float pos = (float)tt * stepT;
                int i0 = (int)pos; i0 = min(i0, NFRAMES - 2);
                float w = pos - (float)i0;
                float2 dd = s_dd[i0];
                float delay = fmaf(w, dd.y, dd.x);
                int z = (int)delay;            // delay >= 100 > 0
                float alfa = delay - (float)z;
                const float4* cfa = (const float4*)s_cf[i0];
                float4 A = cfa[0], Bv = cfa[1], Cv = cfa[2];
                float b0c = fmaf(w, Bv.z, A.x);
                float b1c = fmaf(w, Bv.w, A.y);
                float b2c = fmaf(w, Cv.x, A.z);
                float b3c = fmaf(w, Cv.y, A.w);
                float b4c = fmaf(w, Cv.z, Bv.x);
                float b5c = fmaf(w, Cv.w, Bv.y);
                float na = alfa - 1.0f;        // -(1-alfa)
                float v0 = na * b0c;
                float v1 = fmaf(-alfa, b0c, na * b1c);
                float v2 = fmaf(-alfa, b1c, na * b2c);
                float v3 = fmaf(-alfa, b2c, na * b3c);
                float v4 = fmaf(-alfa, b3c, na * b4c);
                float v5 = fmaf(-alfa, b4c, na * b5c);
                float v6 = -alfa * b5c;
                int qb = ((tt - z - 7) & 1023) << 2;   // hist byte offset
                if (act) {
                    float4* wp = (float4*)&s_ring[(b & (RB - 1)) * 512 + lane * 8];
                    wp[0] = make_float4(v0, v1, v2, v3);
                    wp[1] = make_float4(v4, v5, v6, __int_as_float(qb));
                }
            }
            __threadfence_block();
            if (lane == 0) vs[pidx] = b0 + 8;
        }
    }
}

// ---------------------------------------------------------------- launch
extern "C" void kernel_launch(void* const* d_in, const int* in_sizes, int n_in,
                              void* d_out, int out_size, void* d_ws, size_t ws_size,
                              hipStream_t stream) {
    const float* delay_frames = (const float*)d_in[0];
    const float* excitation   = (const float*)d_in[1];
    const float* raw_coeff    = (const float*)d_in[2];
    const float* raw_gain     = (const float*)d_in[3];
    const float* exc_coeff    = (const float*)d_in[4];
    float* out = (float*)d_out;

    diffks_fused<<<1, 256, 0, stream>>>(delay_frames, excitation, raw_coeff,
                                        raw_gain, exc_coeff, out);
}

// Round 6
// 268.253 us; speedup vs baseline: 1.5181x; 1.5181x over previous
//
#include <hip/hip_runtime.h>
#include <math.h>

// DiffKS round 6 (= round 5 with the global_load_lds immediate-offset fix).
//   Kernel A: per-body SoA tap blobs -> ws. Body b (49 samples): 8 arrays of
//     49 floats (v0..v6, hist-byte-offset q), 1568 B, contiguous.
//   Kernel B: one wave. 16-slot LDS ring (2048 B/slot) filled by
//     global_load_lds (2x dwordx4/body, 12 bodies ahead), manual
//     s_waitcnt vmcnt(12) per 4-body subgroup (never vmcnt(0), no barriers).
//     Tap reads 4 bodies ahead, hist reads 2 ahead, q consumed 2 bodies
//     after read. All hot-loop LDS accesses stride-1 (conflict-free).
//   KC=49: 2*49=98 < 101 = min dependency distance (z>=100).

#define T_SAMPLES 44100
#define NFRAMES   100
#define BURST     2048
#define KC        49
#define NB        900            // 900*49 = 44100
#define HISTSZ    1032           // 1024 ring + 7 mirror + pad
#define RB        16             // ring slots
#define BLOBF     392            // 8*49 floats per body
#define BLOBB     1568           // bytes per body blob
#define WS_BYTES  ((size_t)NB * BLOBB)

typedef const __attribute__((address_space(1))) char GChar;
typedef __attribute__((address_space(3))) char LChar;

__device__ __forceinline__ void dma16(const void* g, void* l) {
    // offset operand must be an immediate constant -> bake into pointers
    __builtin_amdgcn_global_load_lds((GChar*)g, (LChar*)l, 16, 0, 0);
}

// ---------------------------------------------------------------- kernel A
__global__ __launch_bounds__(64) void diffks_taps(
    const float* __restrict__ delay_frames,
    const float* __restrict__ raw_coeff,
    const float* __restrict__ raw_gain,
    float* __restrict__ ws)
{
    const int b = blockIdx.x;
    const int l = threadIdx.x;
    if (l >= KC) return;
    const int t = b * KC + l;
    const float gain  = 0.1f / (1.0f + expf(-raw_gain[0])) + 0.9f;
    const float stepT = 99.0f / (float)(T_SAMPLES - 1);
    float pos = (float)t * stepT;
    int i0 = (int)pos; if (i0 > NFRAMES - 2) i0 = NFRAMES - 2;
    float w = pos - (float)i0;
    float d0 = delay_frames[i0], d1 = delay_frames[i0 + 1];
    float delay = fmaf(w, d1 - d0, d0);
    int z = (int)delay;                    // delay >= 100 > 0
    float alfa = delay - (float)z;

    float bb[6];
    {
        float s0 = 0.f, s1 = 0.f, c0v[6], c1v[6];
        #pragma unroll
        for (int j = 0; j < 6; ++j) {
            c0v[j] = 1.0f / (1.0f + expf(-raw_coeff[i0 * 6 + j]));
            c1v[j] = 1.0f / (1.0f + expf(-raw_coeff[(i0 + 1) * 6 + j]));
            s0 += c0v[j]; s1 += c1v[j];
        }
        float g0 = gain / s0, g1 = gain / s1;
        #pragma unroll
        for (int j = 0; j < 6; ++j) {
            float x0 = c0v[j] * g0, x1 = c1v[j] * g1;
            bb[j] = fmaf(w, x1 - x0, x0);
        }
    }
    float na = alfa - 1.0f;                // -(1-alfa)
    float v[8];
    v[0] = na * bb[0];
    v[1] = fmaf(-alfa, bb[0], na * bb[1]);
    v[2] = fmaf(-alfa, bb[1], na * bb[2]);
    v[3] = fmaf(-alfa, bb[2], na * bb[3]);
    v[4] = fmaf(-alfa, bb[3], na * bb[4]);
    v[5] = fmaf(-alfa, bb[4], na * bb[5]);
    v[6] = -alfa * bb[5];
    v[7] = __int_as_float(((t - z - 7) & 1023) << 2);   // hist byte offset

    float* o = ws + (size_t)b * BLOBF + l;
    #pragma unroll
    for (int k = 0; k < 8; ++k) o[k * KC] = v[k];
}

// ---------------------------------------------------------------- kernel B
__global__ __launch_bounds__(64, 1) void diffks_serial(
    const float* __restrict__ excitation,
    const float* __restrict__ exc_coeff,
    const float* __restrict__ ws,
    float* __restrict__ out)
{
    __shared__ __align__(16) float s_ring[RB * 512];   // 32 KB; aliases scan scratch
    __shared__ float s_x[64][33];                      // burst, padded rows
    __shared__ float s_hist[HISTSZ];
    __shared__ float s_ec[NFRAMES][10];                // exc e0..e4, de0..de4
    __shared__ float s_bound[64][6];

    float (*s_tail)[32] = (float(*)[32])s_ring;        // phase-1 scratch alias

    const int lane = threadIdx.x;
    const float stepE = 99.0f / (float)(BURST - 1);

    // ---- phase 0: stage excitation + exc-coef tables ----
    {
        const float4* ex4 = (const float4*)excitation;
        #pragma unroll
        for (int i = 0; i < 8; ++i) {
            float4 v = ex4[lane + i * 64];
            int t = (lane + i * 64) * 4;
            float* d = &s_x[t >> 5][t & 31];
            d[0] = v.x; d[1] = v.y; d[2] = v.z; d[3] = v.w;
        }
    }
    for (int f = lane; f < NFRAMES - 1; f += 64) {
        #pragma unroll
        for (int k = 0; k < 5; ++k) {
            float a0 = exc_coeff[f * 5 + k];
            float a1 = exc_coeff[(f + 1) * 5 + k];
            s_ec[f][k] = a0;
            s_ec[f][5 + k] = a1 - a0;
        }
    }
    for (int i = lane; i < HISTSZ; i += 64) s_hist[i] = 0.0f;
    __syncthreads();

    // ---- phase 1: excitation LPC via 64-segment state-space scan ----
    {   // pass 1: particular + 5 homogeneous responses per 32-sample segment
        float st[6][5];
        #pragma unroll
        for (int r = 0; r < 6; ++r)
            #pragma unroll
            for (int k = 0; k < 5; ++k) st[r][k] = 0.0f;
        #pragma unroll
        for (int r = 1; r <= 5; ++r) st[r][r - 1] = 1.0f;
        for (int i = 0; i < 32; ++i) {
            int te = lane * 32 + i;
            float pos = (float)te * stepE;
            int i0 = (int)pos; i0 = min(i0, NFRAMES - 2);
            float w = pos - (float)i0;
            const float* e = s_ec[i0];
            float a0 = fmaf(w, e[5], e[0]);
            float a1 = fmaf(w, e[6], e[1]);
            float a2 = fmaf(w, e[7], e[2]);
            float a3 = fmaf(w, e[8], e[3]);
            float a4 = fmaf(w, e[9], e[4]);
            float xv = s_x[lane][i];
            #pragma unroll
            for (int r = 0; r < 6; ++r) {
                float acc = (r == 0) ? xv : 0.0f;
                acc = fmaf(-a0, st[r][0], acc);
                acc = fmaf(-a1, st[r][1], acc);
                acc = fmaf(-a2, st[r][2], acc);
                acc = fmaf(-a3, st[r][3], acc);
                acc = fmaf(-a4, st[r][4], acc);
                st[r][4] = st[r][3]; st[r][3] = st[r][2];
                st[r][2] = st[r][1]; st[r][1] = st[r][0];
                st[r][0] = acc;
            }
        }
        #pragma unroll
        for (int r = 0; r < 6; ++r)
            #pragma unroll
            for (int k = 0; k < 5; ++k) s_tail[lane][r * 5 + k] = st[r][k];
    }
    __syncthreads();
    if (lane == 0) {                       // pass 2: chain boundary states
        float Y[5] = {0.f, 0.f, 0.f, 0.f, 0.f};
        for (int l = 0; l < 64; ++l) {
            #pragma unroll
            for (int c = 0; c < 5; ++c) s_bound[l][c] = Y[c];
            float tl[30];
            #pragma unroll
            for (int j = 0; j < 30; ++j) tl[j] = s_tail[l][j];
            float ny[5];
            #pragma unroll
            for (int k = 0; k < 5; ++k) {
                float acc = tl[k];
                #pragma unroll
                for (int c = 1; c <= 5; ++c)
                    acc = fmaf(tl[c * 5 + k], Y[c - 1], acc);
                ny[k] = acc;
            }
            #pragma unroll
            for (int k = 0; k < 5; ++k) Y[k] = ny[k];
        }
    }
    __syncthreads();
    {   // pass 3: re-run with correct boundary state, filtered burst -> s_x
        float b0 = s_bound[lane][0], b1 = s_bound[lane][1], b2 = s_bound[lane][2];
        float b3 = s_bound[lane][3], b4 = s_bound[lane][4];
        for (int i = 0; i < 32; ++i) {
            int te = lane * 32 + i;
            float pos = (float)te * stepE;
            int i0 = (int)pos; i0 = min(i0, NFRAMES - 2);
            float w = pos - (float)i0;
            const float* e = s_ec[i0];
            float a0 = fmaf(w, e[5], e[0]);
            float a1 = fmaf(w, e[6], e[1]);
            float a2 = fmaf(w, e[7], e[2]);
            float a3 = fmaf(w, e[8], e[3]);
            float a4 = fmaf(w, e[9], e[4]);
            float acc = s_x[lane][i];
            acc = fmaf(-a0, b0, acc);
            acc = fmaf(-a1, b1, acc);
            acc = fmaf(-a2, b2, acc);
            acc = fmaf(-a3, b3, acc);
            acc = fmaf(-a4, b4, acc);
            b4 = b3; b3 = b2; b2 = b1; b1 = b0; b0 = acc;
            s_x[lane][i] = acc;
        }
    }
    __syncthreads();   // LAST barrier — none in the hot loop below

    // ---- phase 2: DMA-pipelined resonator ----
    const char* wsl = (const char*)ws + (size_t)lane * 16;
    // prologue: DMA bodies 0..11 (24 vmcnt ops)
    for (int b = 0; b < 12; ++b) {
        const char* g = wsl + (size_t)b * BLOBB;
        char* ld = (char*)&s_ring[(b & (RB - 1)) * 512];
        dma16(g, ld);
        dma16(g + 1024, ld + 1024);
    }
    __builtin_amdgcn_s_waitcnt(0x0F78);    // vmcnt(8): bodies 0..7 resident

    float tv[4][8], hu[2][7];
    #pragma unroll
    for (int J = 0; J < 4; ++J)
        #pragma unroll
        for (int k = 0; k < 8; ++k) tv[J][k] = s_ring[J * 512 + k * KC + lane];
    #pragma unroll
    for (int J = 0; J < 2; ++J) {
        int qb = __float_as_int(tv[J][7]);
        const float* hq = (const float*)((const char*)s_hist + qb);
        #pragma unroll
        for (int k = 0; k < 7; ++k) hu[J][k] = hq[k];   // zeroed ring -> 0
    }
    int t = lane;
    const bool act = lane < KC;

    // body cc = gb0 + J. consume taps tv[J&3] + hist hu[J&1]; write hist;
    // read hist for cc+2 (q read 2 bodies ago); read taps for cc+4;
    // DMA body cc+12. Store order: out-store BEFORE the 2 DMAs (3 vmcnt
    // ops/body; vmcnt(12) per 4-body subgroup => loads <= body s-5 done).
    #define KSBODY(J, MIX)                                                     \
    {                                                                          \
        const int cc = gb0 + (J);                                              \
        float acc = 0.0f;                                                      \
        if (MIX) { if (act && t < BURST) acc = s_x[t >> 5][t & 31]; }          \
        acc = fmaf(-tv[(J)&3][0], hu[(J)&1][6], acc);                          \
        acc = fmaf(-tv[(J)&3][1], hu[(J)&1][5], acc);                          \
        acc = fmaf(-tv[(J)&3][2], hu[(J)&1][4], acc);                          \
        acc = fmaf(-tv[(J)&3][3], hu[(J)&1][3], acc);                          \
        acc = fmaf(-tv[(J)&3][4], hu[(J)&1][2], acc);                          \
        acc = fmaf(-tv[(J)&3][5], hu[(J)&1][1], acc);                          \
        acc = fmaf(-tv[(J)&3][6], hu[(J)&1][0], acc);                          \
        if (cc < NB) {                                                         \
            int p = t & 1023;                                                  \
            if (act) s_hist[p] = acc;                                          \
            int pm = (cc * KC) & 1023;                                         \
            if (pm >= 976 || pm < 7) {                                         \
                if (act && p < 7) s_hist[p + 1024] = acc;                      \
            }                                                                  \
            if (act) out[t] = acc;                                             \
        }                                                                      \
        {   int qb = __float_as_int(tv[((J)+2)&3][7]);                         \
            const float* hq = (const float*)((const char*)s_hist + qb);        \
            hu[(J)&1][0] = hq[0]; hu[(J)&1][1] = hq[1];                        \
            hu[(J)&1][2] = hq[2]; hu[(J)&1][3] = hq[3];                        \
            hu[(J)&1][4] = hq[4]; hu[(J)&1][5] = hq[5];                        \
            hu[(J)&1][6] = hq[6]; }                                            \
        {   const float* rb = &s_ring[((cc + 4) & (RB - 1)) * 512 + lane];     \
            float* td = tv[(J)&3];                                             \
            td[0] = rb[0*KC]; td[1] = rb[1*KC]; td[2] = rb[2*KC];              \
            td[3] = rb[3*KC]; td[4] = rb[4*KC]; td[5] = rb[5*KC];              \
            td[6] = rb[6*KC]; td[7] = rb[7*KC]; }                              \
        {   int bp = cc + 12; if (bp > NB - 1) bp = NB - 1;                    \
            const char* g = wsl + (size_t)bp * BLOBB;                          \
            char* ld = (char*)&s_ring[(bp & (RB - 1)) * 512];                  \
            dma16(g, ld); dma16(g + 1024, ld + 1024); }                        \
        t += KC;                                                               \
    }

    #define KSGROUP(MIX)                                                       \
        __builtin_amdgcn_s_waitcnt(0x0F7C);                                    \
        KSBODY(0, MIX)  KSBODY(1, MIX)  KSBODY(2, MIX)  KSBODY(3, MIX)         \
        __builtin_amdgcn_s_waitcnt(0x0F7C);                                    \
        KSBODY(4, MIX)  KSBODY(5, MIX)  KSBODY(6, MIX)  KSBODY(7, MIX)         \
        __builtin_amdgcn_s_waitcnt(0x0F7C);                                    \
        KSBODY(8, MIX)  KSBODY(9, MIX)  KSBODY(10, MIX) KSBODY(11, MIX)        \
        __builtin_amdgcn_s_waitcnt(0x0F7C);                                    \
        KSBODY(12, MIX) KSBODY(13, MIX) KSBODY(14, MIX) KSBODY(15, MIX)

    for (int g = 0; g < 3; ++g) {          // bodies 0..47: excitation mix
        const int gb0 = g * 16;
        KSGROUP(true)
    }
    for (int g = 3; g < 57; ++g) {         // bodies 48..911 (>=900 guarded)
        const int gb0 = g * 16;
        KSGROUP(false)
    }
    #undef KSGROUP
    #undef KSBODY
}

// ------------------------------------------------- fallback (round-1 kernel)
#define NCOEF     6
#define NACT      7
#define EXC_ORD   5
#define CHUNK_FB  101
#define NCH_FB    ((T_SAMPLES + CHUNK_FB - 1) / CHUNK_FB)
#define HIST_FB   1024

__global__ __launch_bounds__(128) void diffks_fallback(
    const float* __restrict__ delay_frames,
    const float* __restrict__ excitation,
    const float* __restrict__ raw_coeff,
    const float* __restrict__ raw_gain,
    const float* __restrict__ exc_coeff,
    float* __restrict__ out)
{
    __shared__ float s_a[EXC_ORD][BURST];
    __shared__ float s_x[BURST];
    __shared__ float s_hist[HIST_FB];
    __shared__ __align__(16) float s_coef[NFRAMES][8];
    __shared__ float s_delay[NFRAMES];

    const int tid = threadIdx.x;
    const float gain = 0.1f / (1.0f + expf(-raw_gain[0])) + 0.9f;

    for (int i = tid; i < NFRAMES; i += 128) s_delay[i] = delay_frames[i];
    for (int f = tid; f < NFRAMES; f += 128) {
        float sb[NCOEF]; float s = 0.0f;
        #pragma unroll
        for (int j = 0; j < NCOEF; ++j) {
            sb[j] = 1.0f / (1.0f + expf(-raw_coeff[f * NCOEF + j]));
            s += sb[j];
        }
        float inv = gain / s;
        #pragma unroll
        for (int j = 0; j < NCOEF; ++j) s_coef[f][j] = sb[j] * inv;
        s_coef[f][6] = 0.0f; s_coef[f][7] = 0.0f;
    }
    const float stepE = 99.0f / 2047.0f;
    for (int t = tid; t < BURST; t += 128) {
        float pos = (float)t * stepE;
        int i0 = (int)pos; if (i0 > NFRAMES - 2) i0 = NFRAMES - 2;
        float w = pos - (float)i0;
        const float* c0 = exc_coeff + i0 * EXC_ORD;
        #pragma unroll
        for (int k = 0; k < EXC_ORD; ++k) {
            float a0 = c0[k], a1 = c0[k + EXC_ORD];
            s_a[k][t] = a0 + (a1 - a0) * w;
        }
        s_x[t] = excitation[t];
    }
    for (int i = tid; i < HIST_FB; i += 128) s_hist[i] = 0.0f;
    __syncthreads();

    if (tid == 0) {
        float y1 = 0.f, y2 = 0.f, y3 = 0.f, y4 = 0.f, y5 = 0.f;
        #pragma unroll 4
        for (int t = 0; t < BURST; ++t) {
            float p = s_x[t];
            p = fmaf(-s_a[1][t], y2, p);
            p = fmaf(-s_a[2][t], y3, p);
            p = fmaf(-s_a[3][t], y4, p);
            p = fmaf(-s_a[4][t], y5, p);
            float y = fmaf(-s_a[0][t], y1, p);
            s_x[t] = y;
            y5 = y4; y4 = y3; y3 = y2; y2 = y1; y1 = y;
        }
    }
    __syncthreads();

    const float stepT = 99.0f / (float)(T_SAMPLES - 1);
    for (int c = 0; c < NCH_FB; ++c) {
        int t = c * CHUNK_FB + tid;
        if (tid < CHUNK_FB && t < T_SAMPLES) {
            float pos = (float)t * stepT;
            int i0 = (int)pos; if (i0 > NFRAMES - 2) i0 = NFRAMES - 2;
            float w = pos - (float)i0;
            float d0 = s_delay[i0], d1 = s_delay[i0 + 1];
            float delay = d0 + (d1 - d0) * w;
            int z = (int)delay;
            float alfa = delay - (float)z;
            const float4* f0 = reinterpret_cast<const float4*>(s_coef[i0]);
            const float4* f1 = reinterpret_cast<const float4*>(s_coef[i0 + 1]);
            float4 c0a = f0[0], c0b = f0[1];
            float4 c1a = f1[0], c1b = f1[1];
            float b[NCOEF];
            b[0] = c0a.x + (c1a.x - c0a.x) * w;
            b[1] = c0a.y + (c1a.y - c0a.y) * w;
            b[2] = c0a.z + (c1a.z - c0a.z) * w;
            b[3] = c0a.w + (c1a.w - c0a.w) * w;
            b[4] = c0b.x + (c1b.x - c0b.x) * w;
            b[5] = c0b.y + (c1b.y - c0b.y) * w;
            float oma = 1.0f - alfa;
            float v[NACT];
            v[0] = -oma * b[0];
            #pragma unroll
            for (int j = 1; j <= 5; ++j) v[j] = -(alfa * b[j - 1] + oma * b[j]);
            v[6] = -alfa * b[5];
            float x = (t < BURST) ? s_x[t] : 0.0f;
            int base = t - z - 1;
            float sum = 0.0f;
            #pragma unroll
            for (int j = 0; j < NACT; ++j) {
                int idx = base - j;
                float yv = s_hist[idx & (HIST_FB - 1)];
                if (idx < 0) yv = 0.0f;
                sum = fmaf(v[j], yv, sum);
            }
            float y = x - sum;
            s_hist[t & (HIST_FB - 1)] = y;
            out[t] = y;
        }
        __syncthreads();
    }
}

// ---------------------------------------------------------------- launch
extern "C" void kernel_launch(void* const* d_in, const int* in_sizes, int n_in,
                              void* d_out, int out_size, void* d_ws, size_t ws_size,
                              hipStream_t stream) {
    const float* delay_frames = (const float*)d_in[0];
    const float* excitation   = (const float*)d_in[1];
    const float* raw_coeff    = (const float*)d_in[2];
    const float* raw_gain     = (const float*)d_in[3];
    const float* exc_coeff    = (const float*)d_in[4];
    float* out = (float*)d_out;

    if (ws_size >= WS_BYTES) {
        float* ws = (float*)d_ws;
        diffks_taps<<<NB, 64, 0, stream>>>(delay_frames, raw_coeff, raw_gain, ws);
        diffks_serial<<<1, 64, 0, stream>>>(excitation, exc_coeff, ws, out);
    } else {
        diffks_fallback<<<1, 128, 0, stream>>>(delay_frames, excitation,
                                               raw_coeff, raw_gain, exc_coeff, out);
    }
}

// Round 7
// 239.790 us; speedup vs baseline: 1.6983x; 1.1187x over previous
//
#include <hip/hip_runtime.h>
#include <math.h>

// DiffKS round 7: single kernel, single wave, ZERO hot-loop VMEM reads.
//   Taps are recomputed in-loop from a 6.4 KB LDS frame table (they are
//   linear interpolations of 100 control frames — no 1.4 MB tap stream).
//   Evidence basis: every variant with VMEM reads in the hot loop (r2 reg
//   ring, r3 deep reg ring, r6 global_load_lds DMA) stalls at 350-560
//   cyc/body — compiler-inserted conservative waitcnts. Store-only vmcnt
//   (out[t]) needs no waits.
//   Pipelining: body c consumes taps/hist computed+read 2 bodies earlier;
//   computes taps for c+2 (incl. hist addr q) and issues hist reads for
//   c+2 right after c's hist write. KC=50: 2*50=100 < 101 = min dependency
//   distance (delay >= 100 => z >= 100). 882 bodies * 50 = 44100 exactly.

#define T_SAMPLES 44100
#define NFRAMES   100
#define BURST     2048
#define KC        50
#define NB        882
#define HISTSZ    1032           // 1024 ring + 7 mirror + pad

__global__ __launch_bounds__(64, 1) void diffks_one(
    const float* __restrict__ delay_frames,   // (100,)
    const float* __restrict__ excitation,     // (2048,)
    const float* __restrict__ raw_coeff,      // (100,6)
    const float* __restrict__ raw_gain,       // (1,)
    const float* __restrict__ exc_coeff,      // (100,5)
    float* __restrict__ out)                  // (44100,) f32
{
    __shared__ float s_x[64][33];                      // burst, padded rows
    __shared__ float s_hist[HISTSZ];
    __shared__ __align__(16) float s_frame[NFRAMES][16]; // d0,dd,b0..b5,db0..db5,pad2
    __shared__ float s_nb[NFRAMES][8];                 // normalized loop coefs
    __shared__ float s_ec[NFRAMES][10];                // exc e0..e4, de0..de4
    __shared__ float s_tail[64][32];                   // phase-1 scan tails
    __shared__ float s_bound[64][6];

    const int lane = threadIdx.x;
    const float gain  = 0.1f / (1.0f + expf(-raw_gain[0])) + 0.9f;
    const float stepT = 99.0f / 44099.0f;
    const float stepE = 99.0f / 2047.0f;

    // ---- phase 0a: stage excitation, normalized coefs, exc-coef deltas ----
    {
        const float4* ex4 = (const float4*)excitation;
        #pragma unroll
        for (int i = 0; i < 8; ++i) {
            float4 v = ex4[lane + i * 64];
            int t = (lane + i * 64) * 4;
            float* d = &s_x[t >> 5][t & 31];
            d[0] = v.x; d[1] = v.y; d[2] = v.z; d[3] = v.w;
        }
    }
    for (int f = lane; f < NFRAMES; f += 64) {
        float sb[6]; float s = 0.f;
        #pragma unroll
        for (int j = 0; j < 6; ++j) {
            sb[j] = 1.0f / (1.0f + expf(-raw_coeff[f * 6 + j]));
            s += sb[j];
        }
        float inv = gain / s;
        #pragma unroll
        for (int j = 0; j < 6; ++j) s_nb[f][j] = sb[j] * inv;
    }
    for (int f = lane; f < NFRAMES - 1; f += 64) {
        #pragma unroll
        for (int k = 0; k < 5; ++k) {
            float a0 = exc_coeff[f * 5 + k];
            float a1 = exc_coeff[(f + 1) * 5 + k];
            s_ec[f][k] = a0;
            s_ec[f][5 + k] = a1 - a0;
        }
    }
    for (int i = lane; i < HISTSZ; i += 64) s_hist[i] = 0.0f;
    __syncthreads();
    // ---- phase 0b: frame rows (need s_nb of f and f+1) ----
    for (int f = lane; f < NFRAMES - 1; f += 64) {
        float d0 = delay_frames[f], d1 = delay_frames[f + 1];
        float* r = s_frame[f];
        r[0] = d0; r[1] = d1 - d0;
        #pragma unroll
        for (int j = 0; j < 6; ++j) {
            r[2 + j] = s_nb[f][j];
            r[8 + j] = s_nb[f + 1][j] - s_nb[f][j];
        }
        r[14] = 0.f; r[15] = 0.f;
    }
    __syncthreads();

    // ---- phase 1: excitation LPC via 64-segment state-space scan ----
    {   // pass 1: particular + 5 homogeneous responses per 32-sample segment
        float st[6][5];
        #pragma unroll
        for (int r = 0; r < 6; ++r)
            #pragma unroll
            for (int k = 0; k < 5; ++k) st[r][k] = 0.0f;
        #pragma unroll
        for (int r = 1; r <= 5; ++r) st[r][r - 1] = 1.0f;
        for (int i = 0; i < 32; ++i) {
            int te = lane * 32 + i;
            float pos = (float)te * stepE;
            int i0 = (int)pos; i0 = min(i0, NFRAMES - 2);
            float w = pos - (float)i0;
            const float* e = s_ec[i0];
            float a0 = fmaf(w, e[5], e[0]);
            float a1 = fmaf(w, e[6], e[1]);
            float a2 = fmaf(w, e[7], e[2]);
            float a3 = fmaf(w, e[8], e[3]);
            float a4 = fmaf(w, e[9], e[4]);
            float xv = s_x[lane][i];
            #pragma unroll
            for (int r = 0; r < 6; ++r) {
                float acc = (r == 0) ? xv : 0.0f;
                acc = fmaf(-a0, st[r][0], acc);
                acc = fmaf(-a1, st[r][1], acc);
                acc = fmaf(-a2, st[r][2], acc);
                acc = fmaf(-a3, st[r][3], acc);
                acc = fmaf(-a4, st[r][4], acc);
                st[r][4] = st[r][3]; st[r][3] = st[r][2];
                st[r][2] = st[r][1]; st[r][1] = st[r][0];
                st[r][0] = acc;
            }
        }
        #pragma unroll
        for (int r = 0; r < 6; ++r)
            #pragma unroll
            for (int k = 0; k < 5; ++k) s_tail[lane][r * 5 + k] = st[r][k];
    }
    __syncthreads();
    if (lane == 0) {                       // pass 2: chain boundary states
        float Y[5] = {0.f, 0.f, 0.f, 0.f, 0.f};
        for (int l = 0; l < 64; ++l) {
            #pragma unroll
            for (int c = 0; c < 5; ++c) s_bound[l][c] = Y[c];
            float tl[30];
            #pragma unroll
            for (int j = 0; j < 30; ++j) tl[j] = s_tail[l][j];
            float ny[5];
            #pragma unroll
            for (int k = 0; k < 5; ++k) {
                float acc = tl[k];
                #pragma unroll
                for (int c = 1; c <= 5; ++c)
                    acc = fmaf(tl[c * 5 + k], Y[c - 1], acc);
                ny[k] = acc;
            }
            #pragma unroll
            for (int k = 0; k < 5; ++k) Y[k] = ny[k];
        }
    }
    __syncthreads();
    {   // pass 3: re-run with correct boundary state, filtered burst -> s_x
        float b0 = s_bound[lane][0], b1 = s_bound[lane][1], b2 = s_bound[lane][2];
        float b3 = s_bound[lane][3], b4 = s_bound[lane][4];
        for (int i = 0; i < 32; ++i) {
            int te = lane * 32 + i;
            float pos = (float)te * stepE;
            int i0 = (int)pos; i0 = min(i0, NFRAMES - 2);
            float w = pos - (float)i0;
            const float* e = s_ec[i0];
            float a0 = fmaf(w, e[5], e[0]);
            float a1 = fmaf(w, e[6], e[1]);
            float a2 = fmaf(w, e[7], e[2]);
            float a3 = fmaf(w, e[8], e[3]);
            float a4 = fmaf(w, e[9], e[4]);
            float acc = s_x[lane][i];
            acc = fmaf(-a0, b0, acc);
            acc = fmaf(-a1, b1, acc);
            acc = fmaf(-a2, b2, acc);
            acc = fmaf(-a3, b3, acc);
            acc = fmaf(-a4, b4, acc);
            b4 = b3; b3 = b2; b2 = b1; b1 = b0; b0 = acc;
            s_x[lane][i] = acc;
        }
    }
    __syncthreads();   // LAST barrier — none in the hot loop below

    // ---- phase 2: resonator, taps recomputed in-loop, 2-ahead pipelining ----
    const bool act = lane < KC;
    float vb[2][7], hu[2][7];
    int t = lane;

    // MKTAPS: compute taps for sample TT (a body 2 ahead) into vb[PAR] and
    // issue its 7 hist reads into hu[PAR]. Placed AFTER the current body's
    // hist write => in-order LDS gives reads all writes <= current body.
    #define MKTAPS(PAR, TT)                                                    \
    {                                                                          \
        float pos = (float)(TT) * stepT;                                       \
        int i0 = (int)pos; i0 = min(i0, NFRAMES - 2);                          \
        float w = pos - (float)i0;                                             \
        const float4* R = (const float4*)s_frame[i0];                          \
        float4 r0 = R[0], r1 = R[1], r2 = R[2], r3 = R[3];                     \
        float dl = fmaf(w, r0.y, r0.x);                                        \
        int z = (int)dl;                                                       \
        float alfa = dl - (float)z;                                            \
        float b0 = fmaf(w, r2.x, r0.z), b1 = fmaf(w, r2.y, r0.w);              \
        float b2 = fmaf(w, r2.z, r1.x), b3 = fmaf(w, r2.w, r1.y);              \
        float b4 = fmaf(w, r3.x, r1.z), b5 = fmaf(w, r3.y, r1.w);              \
        float na = alfa - 1.0f;                                                \
        vb[PAR][0] = na * b0;                                                  \
        vb[PAR][1] = fmaf(-alfa, b0, na * b1);                                 \
        vb[PAR][2] = fmaf(-alfa, b1, na * b2);                                 \
        vb[PAR][3] = fmaf(-alfa, b2, na * b3);                                 \
        vb[PAR][4] = fmaf(-alfa, b3, na * b4);                                 \
        vb[PAR][5] = fmaf(-alfa, b4, na * b5);                                 \
        vb[PAR][6] = -alfa * b5;                                               \
        int q = ((TT) - z - 7) & 1023;                                         \
        const float* hq = &s_hist[q];                                          \
        hu[PAR][0] = hq[0]; hu[PAR][1] = hq[1]; hu[PAR][2] = hq[2];            \
        hu[PAR][3] = hq[3]; hu[PAR][4] = hq[4]; hu[PAR][5] = hq[5];            \
        hu[PAR][6] = hq[6];                                                    \
    }

    // prologue: bodies 0 and 1 (their hist deps are all idx<0 -> zeroed ring)
    MKTAPS(0, t)
    MKTAPS(1, t + KC)

    // body: consume vb/hu parity (J&1); write hist+out; prep body cc+2.
    #define KSBODY(J, MIX)                                                     \
    {                                                                          \
        const int par = (J) & 1;                                               \
        float acc = 0.0f;                                                      \
        if (MIX) { if (act && t < BURST) acc = s_x[t >> 5][t & 31]; }          \
        acc = fmaf(-vb[par][0], hu[par][6], acc);                              \
        acc = fmaf(-vb[par][1], hu[par][5], acc);                              \
        acc = fmaf(-vb[par][2], hu[par][4], acc);                              \
        acc = fmaf(-vb[par][3], hu[par][3], acc);                              \
        acc = fmaf(-vb[par][4], hu[par][2], acc);                              \
        acc = fmaf(-vb[par][5], hu[par][1], acc);                              \
        acc = fmaf(-vb[par][6], hu[par][0], acc);                              \
        int p = t & 1023;                                                      \
        if (act) s_hist[p] = acc;                                              \
        {   int pm = ((cb + (J)) * KC) & 1023;                                 \
            if (pm >= 975 || pm < 7) {                                         \
                if (act && p < 7) s_hist[p + 1024] = acc;                      \
            } }                                                                \
        if (act) out[t] = acc;                                                 \
        MKTAPS(par, t + 2 * KC)                                                \
        t += KC;                                                               \
    }

    // bodies 0..41 may mix excitation (t < 2048); run 42 MIX bodies
    for (int cb = 0; cb < 42; cb += 6) {
        KSBODY(0, true) KSBODY(1, true) KSBODY(2, true)
        KSBODY(3, true) KSBODY(4, true) KSBODY(5, true)
    }
    // bodies 42..881: steady state (840 = 140*6)
    for (int cb = 42; cb < NB; cb += 6) {
        KSBODY(0, false) KSBODY(1, false) KSBODY(2, false)
        KSBODY(3, false) KSBODY(4, false) KSBODY(5, false)
    }
    #undef KSBODY
    #undef MKTAPS
}

// ---------------------------------------------------------------- launch
extern "C" void kernel_launch(void* const* d_in, const int* in_sizes, int n_in,
                              void* d_out, int out_size, void* d_ws, size_t ws_size,
                              hipStream_t stream) {
    const float* delay_frames = (const float*)d_in[0];
    const float* excitation   = (const float*)d_in[1];
    const float* raw_coeff    = (const float*)d_in[2];
    const float* raw_gain     = (const float*)d_in[3];
    const float* exc_coeff    = (const float*)d_in[4];
    float* out = (float*)d_out;

    diffks_one<<<1, 64, 0, stream>>>(delay_frames, excitation, raw_coeff,
                                     raw_gain, exc_coeff, out);
}

// Round 8
// 233.749 us; speedup vs baseline: 1.7422x; 1.0258x over previous
//
#include <hip/hip_runtime.h>
#include <math.h>

// DiffKS round 8: r7 + one more pipeline stage for the frame-table reads.
//   r7 post-mortem: frame-row ds_read_b128s were issued and consumed inside
//   the same body -> ~300 cyc exposed LDS latency+queue drain per body
//   (VALUBusy 10% on the active CU). Now EVERY hot-loop LDS read has >=1.2
//   bodies of issue->use distance:
//     body c: [A] fma-consume taps vb[c]/hist hu[c] (read >=1.2 bodies ago)
//             [B] hist write + mirror + out store
//             [C] compute taps+q for c+2 from frame regs FR (read in c-2)
//             [D] issue hist reads for c+2 (deps <= c: 2*50=100 < 101 OK)
//             [E] issue frame-row reads for c+4 into FR slot (c&3)
//   Zero hot-loop VMEM reads (r7-proven), zero barriers, one wave.

#define T_SAMPLES 44100
#define NFRAMES   100
#define BURST     2048
#define KC        50
#define NB        882            // 882*50 = 44100
#define HISTSZ    1032           // 1024 ring + 7 mirror + pad

__global__ __launch_bounds__(64, 1) void diffks_one(
    const float* __restrict__ delay_frames,   // (100,)
    const float* __restrict__ excitation,     // (2048,)
    const float* __restrict__ raw_coeff,      // (100,6)
    const float* __restrict__ raw_gain,       // (1,)
    const float* __restrict__ exc_coeff,      // (100,5)
    float* __restrict__ out)                  // (44100,) f32
{
    __shared__ float s_x[64][33];                      // burst, padded rows
    __shared__ float s_hist[HISTSZ];
    __shared__ __align__(16) float s_frame[NFRAMES][16]; // d0,dd,b0..b5,db0..db5,pad
    __shared__ float s_nb[NFRAMES][8];                 // normalized loop coefs
    __shared__ float s_ec[NFRAMES][10];                // exc e0..e4, de0..de4
    __shared__ float s_tail[64][32];                   // phase-1 scan tails
    __shared__ float s_bound[64][6];

    const int lane = threadIdx.x;
    const float gain  = 0.1f / (1.0f + expf(-raw_gain[0])) + 0.9f;
    const float stepT = 99.0f / 44099.0f;
    const float stepE = 99.0f / 2047.0f;

    // ---- phase 0a: stage excitation, normalized coefs, exc-coef deltas ----
    {
        const float4* ex4 = (const float4*)excitation;
        #pragma unroll
        for (int i = 0; i < 8; ++i) {
            float4 v = ex4[lane + i * 64];
            int t = (lane + i * 64) * 4;
            float* d = &s_x[t >> 5][t & 31];
            d[0] = v.x; d[1] = v.y; d[2] = v.z; d[3] = v.w;
        }
    }
    for (int f = lane; f < NFRAMES; f += 64) {
        float sb[6]; float s = 0.f;
        #pragma unroll
        for (int j = 0; j < 6; ++j) {
            sb[j] = 1.0f / (1.0f + expf(-raw_coeff[f * 6 + j]));
            s += sb[j];
        }
        float inv = gain / s;
        #pragma unroll
        for (int j = 0; j < 6; ++j) s_nb[f][j] = sb[j] * inv;
    }
    for (int f = lane; f < NFRAMES - 1; f += 64) {
        #pragma unroll
        for (int k = 0; k < 5; ++k) {
            float a0 = exc_coeff[f * 5 + k];
            float a1 = exc_coeff[(f + 1) * 5 + k];
            s_ec[f][k] = a0;
            s_ec[f][5 + k] = a1 - a0;
        }
    }
    for (int i = lane; i < HISTSZ; i += 64) s_hist[i] = 0.0f;
    __syncthreads();
    // ---- phase 0b: frame rows (need s_nb of f and f+1) ----
    for (int f = lane; f < NFRAMES - 1; f += 64) {
        float d0 = delay_frames[f], d1 = delay_frames[f + 1];
        float* r = s_frame[f];
        r[0] = d0; r[1] = d1 - d0;
        #pragma unroll
        for (int j = 0; j < 6; ++j) {
            r[2 + j] = s_nb[f][j];
            r[8 + j] = s_nb[f + 1][j] - s_nb[f][j];
        }
        r[14] = 0.f; r[15] = 0.f;
    }
    __syncthreads();

    // ---- phase 1: excitation LPC via 64-segment state-space scan ----
    {   // pass 1: particular + 5 homogeneous responses per 32-sample segment
        float st[6][5];
        #pragma unroll
        for (int r = 0; r < 6; ++r)
            #pragma unroll
            for (int k = 0; k < 5; ++k) st[r][k] = 0.0f;
        #pragma unroll
        for (int r = 1; r <= 5; ++r) st[r][r - 1] = 1.0f;
        for (int i = 0; i < 32; ++i) {
            int te = lane * 32 + i;
            float pos = (float)te * stepE;
            int i0 = (int)pos; i0 = min(i0, NFRAMES - 2);
            float w = pos - (float)i0;
            const float* e = s_ec[i0];
            float a0 = fmaf(w, e[5], e[0]);
            float a1 = fmaf(w, e[6], e[1]);
            float a2 = fmaf(w, e[7], e[2]);
            float a3 = fmaf(w, e[8], e[3]);
            float a4 = fmaf(w, e[9], e[4]);
            float xv = s_x[lane][i];
            #pragma unroll
            for (int r = 0; r < 6; ++r) {
                float acc = (r == 0) ? xv : 0.0f;
                acc = fmaf(-a0, st[r][0], acc);
                acc = fmaf(-a1, st[r][1], acc);
                acc = fmaf(-a2, st[r][2], acc);
                acc = fmaf(-a3, st[r][3], acc);
                acc = fmaf(-a4, st[r][4], acc);
                st[r][4] = st[r][3]; st[r][3] = st[r][2];
                st[r][2] = st[r][1]; st[r][1] = st[r][0];
                st[r][0] = acc;
            }
        }
        #pragma unroll
        for (int r = 0; r < 6; ++r)
            #pragma unroll
            for (int k = 0; k < 5; ++k) s_tail[lane][r * 5 + k] = st[r][k];
    }
    __syncthreads();
    if (lane == 0) {                       // pass 2: chain boundary states
        float Y[5] = {0.f, 0.f, 0.f, 0.f, 0.f};
        for (int l = 0; l < 64; ++l) {
            #pragma unroll
            for (int c = 0; c < 5; ++c) s_bound[l][c] = Y[c];
            float tl[30];
            #pragma unroll
            for (int j = 0; j < 30; ++j) tl[j] = s_tail[l][j];
            float ny[5];
            #pragma unroll
            for (int k = 0; k < 5; ++k) {
                float acc = tl[k];
                #pragma unroll
                for (int c = 1; c <= 5; ++c)
                    acc = fmaf(tl[c * 5 + k], Y[c - 1], acc);
                ny[k] = acc;
            }
            #pragma unroll
            for (int k = 0; k < 5; ++k) Y[k] = ny[k];
        }
    }
    __syncthreads();
    {   // pass 3: re-run with correct boundary state, filtered burst -> s_x
        float b0 = s_bound[lane][0], b1 = s_bound[lane][1], b2 = s_bound[lane][2];
        float b3 = s_bound[lane][3], b4 = s_bound[lane][4];
        for (int i = 0; i < 32; ++i) {
            int te = lane * 32 + i;
            float pos = (float)te * stepE;
            int i0 = (int)pos; i0 = min(i0, NFRAMES - 2);
            float w = pos - (float)i0;
            const float* e = s_ec[i0];
            float a0 = fmaf(w, e[5], e[0]);
            float a1 = fmaf(w, e[6], e[1]);
            float a2 = fmaf(w, e[7], e[2]);
            float a3 = fmaf(w, e[8], e[3]);
            float a4 = fmaf(w, e[9], e[4]);
            float acc = s_x[lane][i];
            acc = fmaf(-a0, b0, acc);
            acc = fmaf(-a1, b1, acc);
            acc = fmaf(-a2, b2, acc);
            acc = fmaf(-a3, b3, acc);
            acc = fmaf(-a4, b4, acc);
            b4 = b3; b3 = b2; b2 = b1; b1 = b0; b0 = acc;
            s_x[lane][i] = acc;
        }
    }
    __syncthreads();   // LAST barrier — none in the hot loop below

    // ---- phase 2: resonator, 3-stage pipeline (frame 4-ahead, hist 2-ahead) ----
    const bool act = lane < KC;
    float4 FR[4][4];     // frame rows for upcoming bodies; slot = body & 3
    float  vb[2][7], hu[2][7];
    int t = lane;

    // FRFETCH(slot, TT): issue 4 frame-row reads for sample TT into FR[slot]
    #define FRFETCH(SLOT, TT)                                                  \
    {                                                                          \
        int tc = min((TT), T_SAMPLES - 1);                                     \
        float pos = (float)tc * stepT;                                         \
        int i0 = min((int)pos, NFRAMES - 2);                                   \
        const float4* R = (const float4*)s_frame[i0];                          \
        FR[SLOT][0] = R[0]; FR[SLOT][1] = R[1];                                \
        FR[SLOT][2] = R[2]; FR[SLOT][3] = R[3];                                \
    }

    // MKTAPS(par, slot, TT): taps for sample TT from FR[slot]; issue its 7
    // hist reads. Must be placed AFTER the write of the body 2 before TT's.
    #define MKTAPS(PAR, SLOT, TT)                                              \
    {                                                                          \
        int tc = min((TT), T_SAMPLES - 1);                                     \
        float pos = (float)tc * stepT;                                         \
        int i0 = min((int)pos, NFRAMES - 2);                                   \
        float w = pos - (float)i0;                                             \
        float4 r0 = FR[SLOT][0], r1 = FR[SLOT][1];                             \
        float4 r2 = FR[SLOT][2], r3 = FR[SLOT][3];                             \
        float dl = fmaf(w, r0.y, r0.x);                                        \
        int z = (int)dl;                                                       \
        float alfa = dl - (float)z;                                            \
        float b0 = fmaf(w, r2.x, r0.z), b1 = fmaf(w, r2.y, r0.w);              \
        float b2 = fmaf(w, r2.z, r1.x), b3 = fmaf(w, r2.w, r1.y);              \
        float b4 = fmaf(w, r3.x, r1.z), b5 = fmaf(w, r3.y, r1.w);              \
        float na = alfa - 1.0f;                                                \
        vb[PAR][0] = na * b0;                                                  \
        vb[PAR][1] = fmaf(-alfa, b0, na * b1);                                 \
        vb[PAR][2] = fmaf(-alfa, b1, na * b2);                                 \
        vb[PAR][3] = fmaf(-alfa, b2, na * b3);                                 \
        vb[PAR][4] = fmaf(-alfa, b3, na * b4);                                 \
        vb[PAR][5] = fmaf(-alfa, b4, na * b5);                                 \
        vb[PAR][6] = -alfa * b5;                                               \
        int q = (tc - z - 7) & 1023;                                           \
        const float* hq = &s_hist[q];                                          \
        hu[PAR][0] = hq[0]; hu[PAR][1] = hq[1]; hu[PAR][2] = hq[2];            \
        hu[PAR][3] = hq[3]; hu[PAR][4] = hq[4]; hu[PAR][5] = hq[5];            \
        hu[PAR][6] = hq[6];                                                    \
    }

    // prologue: frame rows for bodies 0..3; taps+hist reads for bodies 0,1
    // (their hist deps all have idx<0 -> zeroed ring gives exact 0).
    FRFETCH(0, t)
    FRFETCH(1, t + KC)
    FRFETCH(2, t + 2 * KC)
    FRFETCH(3, t + 3 * KC)
    MKTAPS(0, 0, t)
    MKTAPS(1, 1, t + KC)

    // body cc = cb + J  (cb % 4 == 0, so parity = J&1, FR slots = J&3)
    #define KSBODY(J, MIX)                                                     \
    {                                                                          \
        const int par = (J) & 1;                                               \
        float acc = 0.0f;                                                      \
        if (MIX) { if (act && t < BURST) acc = s_x[t >> 5][t & 31]; }          \
        acc = fmaf(-vb[par][0], hu[par][6], acc);                              \
        acc = fmaf(-vb[par][1], hu[par][5], acc);                              \
        acc = fmaf(-vb[par][2], hu[par][4], acc);                              \
        acc = fmaf(-vb[par][3], hu[par][3], acc);                              \
        acc = fmaf(-vb[par][4], hu[par][2], acc);                              \
        acc = fmaf(-vb[par][5], hu[par][1], acc);                              \
        acc = fmaf(-vb[par][6], hu[par][0], acc);                              \
        int p = t & 1023;                                                      \
        if (act) s_hist[p] = acc;                                              \
        {   int pm = ((cb + (J)) * KC) & 1023;                                 \
            if (pm >= 975 || pm < 7) {                                         \
                if (act && p < 7) s_hist[p + 1024] = acc;                      \
            } }                                                                \
        if (act) out[t] = acc;                                                 \
        MKTAPS(par, ((J) + 2) & 3, t + 2 * KC)                                 \
        FRFETCH((J) & 3, t + 4 * KC)                                           \
        t += KC;                                                               \
    }

    // bodies 0..43: excitation mix possible (t < 2048 for cc <= 40)
    for (int cb = 0; cb < 44; cb += 4) {
        KSBODY(0, true) KSBODY(1, true) KSBODY(2, true) KSBODY(3, true)
    }
    // bodies 44..875: steady state (832 = 4*208)
    for (int cb = 44; cb < 876; cb += 4) {
        KSBODY(0, false) KSBODY(1, false) KSBODY(2, false) KSBODY(3, false)
    }
    // tail: bodies 876..881 (all < NB; their MKTAPS/FRFETCH clamp TT)
    {
        const int cb = 876;
        KSBODY(0, false) KSBODY(1, false) KSBODY(2, false) KSBODY(3, false)
    }
    {
        const int cb = 880;
        KSBODY(0, false) KSBODY(1, false)
    }
    #undef KSBODY
    #undef MKTAPS
    #undef FRFETCH
}

// ---------------------------------------------------------------- launch
extern "C" void kernel_launch(void* const* d_in, const int* in_sizes, int n_in,
                              void* d_out, int out_size, void* d_ws, size_t ws_size,
                              hipStream_t stream) {
    const float* delay_frames = (const float*)d_in[0];
    const float* excitation   = (const float*)d_in[1];
    const float* raw_coeff    = (const float*)d_in[2];
    const float* raw_gain     = (const float*)d_in[3];
    const float* exc_coeff    = (const float*)d_in[4];
    float* out = (float*)d_out;

    diffks_one<<<1, 64, 0, stream>>>(delay_frames, excitation, raw_coeff,
                                     raw_gain, exc_coeff, out);
}